// Round 14
// baseline (323.542 us; speedup 1.0000x reference)
//
#include <hip/hip_runtime.h>

#define D 128
#define RPW 8            // rows per wave (f32 GCN gemm)
#define ROWS_PB 32       // rows per block (4 waves * 8)

typedef __attribute__((ext_vector_type(8))) short short8;
typedef __attribute__((ext_vector_type(4))) float f32x4;

static __device__ __forceinline__ ushort f2bf(float f) {
    unsigned u = __float_as_uint(f);
    unsigned r = (u + 0x7fffu + ((u >> 16) & 1u)) >> 16;   // round-to-nearest-even
    return (ushort)r;
}

// ---------------- shared gemm compute (input already staged in sh) -----------
static __device__ __forceinline__ void gemm_compute(const float* sw, float (*sh)[D],
                                                    ushort* __restrict__ outb,
                                                    int N, int row0, int tid) {
    int wid = tid >> 6, lane = tid & 63;
    int rb = wid * RPW;
    float acc0[RPW], acc1[RPW];
#pragma unroll
    for (int r = 0; r < RPW; ++r) { acc0[r] = 0.f; acc1[r] = 0.f; }
    for (int k = 0; k < D; k += 4) {
        float w0[4], w1[4];
#pragma unroll
        for (int kk = 0; kk < 4; ++kk) {
            w0[kk] = sw[(k + kk) * D + lane];
            w1[kk] = sw[(k + kk) * D + lane + 64];
        }
#pragma unroll
        for (int r = 0; r < RPW; ++r) {
            float4 a4 = *(const float4*)&sh[rb + r][k];
            acc0[r] = fmaf(a4.x, w0[0], acc0[r]); acc1[r] = fmaf(a4.x, w1[0], acc1[r]);
            acc0[r] = fmaf(a4.y, w0[1], acc0[r]); acc1[r] = fmaf(a4.y, w1[1], acc1[r]);
            acc0[r] = fmaf(a4.z, w0[2], acc0[r]); acc1[r] = fmaf(a4.z, w1[2], acc1[r]);
            acc0[r] = fmaf(a4.w, w0[3], acc0[r]); acc1[r] = fmaf(a4.w, w1[3], acc1[r]);
        }
    }
#pragma unroll
    for (int r = 0; r < RPW; ++r) {
        int row = row0 + rb + r;
        if (row < N) {
            outb[(size_t)row * D + lane] = f2bf(acc0[r]);
            outb[(size_t)row * D + lane + 64] = f2bf(acc1[r]);
        }
    }
}

// ---------------- gemm body, f32 input ---------------------------------------
static __device__ __forceinline__ void gemm_body(float* sw, float (*sh)[D],
                                                 const float* __restrict__ in,
                                                 const float* __restrict__ W,
                                                 ushort* __restrict__ outb,
                                                 int N, int bid, int tid) {
    int row0 = bid * ROWS_PB;
    for (int j = tid; j < D * D / 4; j += 256)
        ((float4*)sw)[j] = ((const float4*)W)[j];
    for (int i = tid; i < ROWS_PB * (D / 4); i += 256) {
        int r = i >> 5, c4 = i & 31;
        int row = row0 + r;
        float4 v = (row < N) ? ((const float4*)(in + (size_t)row * D))[c4]
                             : make_float4(0.f, 0.f, 0.f, 0.f);
        ((float4*)sh)[i] = v;
    }
    __syncthreads();
    gemm_compute(sw, sh, outb, N, row0, tid);
}

// ---------------- stage 1: gemm0 | slot0 | convW (1:2 interleave) ------------
__global__ __launch_bounds__(256) void fused_gs0(const float* __restrict__ x,
                                                 const float* __restrict__ W0,
                                                 ushort* __restrict__ P, int N,
                                                 const int* __restrict__ dst0,
                                                 int* __restrict__ counts0,
                                                 ushort* __restrict__ pl0, int E,
                                                 const float* __restrict__ Wx,
                                                 const float* __restrict__ Wh,
                                                 ushort* __restrict__ wxt,
                                                 ushort* __restrict__ wht, int GB) {
    __shared__ float sw[D * D];          // 64 KB
    __shared__ float sh[ROWS_PB][D];     // 16 KB
    int bid = blockIdx.x, tid = threadIdx.x;
    int three = GB * 3;
    if (bid < three) {
        int g = bid / 3, j = bid - g * 3;
        if (j == 0) {
            gemm_body(sw, sh, x, W0, P, N, g, tid);
        } else {
            int i = (g * 2 + (j - 1)) * 256 + tid;
            if (i < E)
                pl0[i] = (ushort)atomicAdd(&counts0[dst0[i]], 1);
        }
    } else {
        int i = (bid - three) * 256 + tid;
        if (i < 384 * 128) {
            int c = i >> 7, k = i & 127;
            wxt[i] = f2bf(Wx[(size_t)k * 384 + c]);
            wht[i] = f2bf(Wh[(size_t)k * 384 + c]);
        }
    }
}

// ---------------- stage 2: place0 | slot1 (1:1, no LDS) ----------------------
__global__ void fused_ps1(const int* __restrict__ src0, const int* __restrict__ dst0,
                          const float* __restrict__ w0,
                          const int* __restrict__ offsets0,
                          const ushort* __restrict__ pl0, int2* __restrict__ srcw0,
                          const int* __restrict__ dst1, int* __restrict__ counts1,
                          ushort* __restrict__ pl1, int E) {
    int bid = blockIdx.x, tid = threadIdx.x;
    int g = bid >> 1;
    int i = g * 256 + tid;
    if (i >= E) return;
    if ((bid & 1) == 0) {
        int p = offsets0[dst0[i]] + (int)pl0[i];
        srcw0[p] = make_int2(src0[i], __float_as_int(w0[i]));
    } else {
        pl1[i] = (ushort)atomicAdd(&counts1[dst1[i]], 1);
    }
}

// ---------------- gather helper (bf16 support rows) --------------------------
static __device__ __forceinline__ void gather_row(const ushort* __restrict__ base,
                                                  const int2* __restrict__ srcw,
                                                  int lo, int hi,
                                                  float& ax, float& ay) {
    ax = 0.f; ay = 0.f;
    int j = lo;
    for (; j + 8 <= hi; j += 8) {
        int2 s[8];
        uint v[8];
#pragma unroll
        for (int u = 0; u < 8; ++u) s[u] = srcw[j + u];
#pragma unroll
        for (int u = 0; u < 8; ++u)
            v[u] = *(const uint*)(base + ((size_t)s[u].x << 7));
#pragma unroll
        for (int u = 0; u < 8; ++u) {
            float wt = __int_as_float(s[u].y);
            ax = fmaf(wt, __uint_as_float(v[u] << 16), ax);
            ay = fmaf(wt, __uint_as_float(v[u] & 0xffff0000u), ay);
        }
    }
    for (; j < hi; ++j) {
        int2 sw = srcw[j];
        float wt = __int_as_float(sw.y);
        uint v = *(const uint*)(base + ((size_t)sw.x << 7));
        ax = fmaf(wt, __uint_as_float(v << 16), ax);
        ay = fmaf(wt, __uint_as_float(v & 0xffff0000u), ay);
    }
}

static __device__ __forceinline__ void gather_node_body(const ushort* __restrict__ supb,
                                                        const int2* __restrict__ srcw,
                                                        const int* __restrict__ offsets,
                                                        const float* __restrict__ bias,
                                                        ushort* __restrict__ outb,
                                                        int node, int lane, int N) {
    if (node >= N) return;
    int lo = offsets[node], hi = offsets[node + 1];
    int c = lane * 2;
    float ax, ay;
    gather_row(supb + c, srcw, lo, hi, ax, ay);
    float2 bi = *(const float2*)(bias + c);
    uint pk = ((uint)f2bf(fmaxf(ay + bi.y, 0.f)) << 16) | (uint)f2bf(fmaxf(ax + bi.x, 0.f));
    *(uint*)(outb + (size_t)node * D + c) = pk;
}

// ---------------- stage 3: gather0 | place1 (4:1, no LDS) --------------------
__global__ void fused_gp1(const ushort* __restrict__ P, const int2* __restrict__ srcw0,
                          const int* __restrict__ offsets0,
                          const float* __restrict__ b0, ushort* __restrict__ Q, int N,
                          const int* __restrict__ src1, const int* __restrict__ dst1,
                          const float* __restrict__ w1,
                          const int* __restrict__ offsets1,
                          const ushort* __restrict__ pl1,
                          int2* __restrict__ srcw1, int E) {
    int bid = blockIdx.x, tid = threadIdx.x;
    int g = bid / 5, j = bid - g * 5;
    if (j < 4) {
        int node = (g * 4 + j) * 4 + (tid >> 6);
        gather_node_body(P, srcw0, offsets0, b0, Q, node, tid & 63, N);
    } else {
        int e = g * 256 + tid;
        if (e < E) {
            int p = offsets1[dst1[e]] + (int)pl1[e];
            srcw1[p] = make_int2(src1[e], __float_as_int(w1[e]));
        }
    }
}

// ---------------- standalone gather (layer 1) --------------------------------
__global__ void gather_nodes_bf(const ushort* __restrict__ supb,
                                const int2* __restrict__ srcw,
                                const int* __restrict__ offsets,
                                const float* __restrict__ bias,
                                ushort* __restrict__ outb, int N) {
    int node = (blockIdx.x * blockDim.x + threadIdx.x) >> 6;
    gather_node_body(supb, srcw, offsets, bias, outb, node, threadIdx.x & 63, N);
}

// ---------------- standalone gemm, bf16 input --------------------------------
__global__ __launch_bounds__(256) void gemm_rowbatch_bfin(const ushort* __restrict__ in,
                                                          const float* __restrict__ W,
                                                          ushort* __restrict__ outb, int N) {
    __shared__ float sw[D * D];
    __shared__ float sh[ROWS_PB][D];
    int tid = threadIdx.x;
    int row0 = blockIdx.x * ROWS_PB;
    for (int j = tid; j < D * D / 4; j += 256)
        ((float4*)sw)[j] = ((const float4*)W)[j];
    for (int i = tid; i < ROWS_PB * (D / 4); i += 256) {
        int r = i >> 5, c4 = i & 31;
        int row = row0 + r;
        float4 v;
        if (row < N) {
            uint2 u = ((const uint2*)(in + (size_t)row * D))[c4];
            v.x = __uint_as_float(u.x << 16);
            v.y = __uint_as_float(u.x & 0xffff0000u);
            v.z = __uint_as_float(u.y << 16);
            v.w = __uint_as_float(u.y & 0xffff0000u);
        } else {
            v = make_float4(0.f, 0.f, 0.f, 0.f);
        }
        ((float4*)sh)[i] = v;
    }
    __syncthreads();
    gemm_compute(sw, sh, outb, N, row0, tid);
}

// ---------------- zero ints --------------------------------------------------
__global__ void zero_int4(int4* __restrict__ p, int n4) {
    int i = blockIdx.x * blockDim.x + threadIdx.x;
    if (i < n4) p[i] = make_int4(0, 0, 0, 0);
}

// ---------------- multi-block scan: pass 1 (block partial sums) --------------
__global__ __launch_bounds__(256) void scan_partial(const int4* __restrict__ counts4,
                                                    int* __restrict__ bsum) {
    int b = blockIdx.x, t = threadIdx.x;
    int4 c0 = counts4[(size_t)b * 512 + t * 2];
    int4 c1 = counts4[(size_t)b * 512 + t * 2 + 1];
    int s = c0.x + c0.y + c0.z + c0.w + c1.x + c1.y + c1.z + c1.w;
#pragma unroll
    for (int d = 1; d < 64; d <<= 1) s += __shfl_xor(s, d);
    __shared__ int ws[4];
    if ((t & 63) == 0) ws[t >> 6] = s;
    __syncthreads();
    if (t == 0) bsum[b] = ws[0] + ws[1] + ws[2] + ws[3];
}

// ---------------- multi-block scan: pass 2 (scan of block sums, 1 wave) ------
__global__ void scan_base(const int* __restrict__ bsum, int* __restrict__ bbase, int nb) {
    int lane = threadIdx.x;   // launched with 64 threads
    int run = 0;
    for (int c = 0; c < nb; c += 64) {
        int v = (c + lane < nb) ? bsum[c + lane] : 0;
        int inc = v;
#pragma unroll
        for (int d = 1; d < 64; d <<= 1) {
            int y = __shfl_up(inc, d);
            if (lane >= d) inc += y;
        }
        if (c + lane < nb) bbase[c + lane] = run + inc - v;
        run += __shfl(inc, 63);
    }
}

// ---------------- multi-block scan: pass 3 (apply) ---------------------------
__global__ __launch_bounds__(256) void scan_apply(const int4* __restrict__ counts4,
                                                  const int* __restrict__ bbase,
                                                  int4* __restrict__ off4) {
    __shared__ int ts[256];
    int b = blockIdx.x, t = threadIdx.x;
    int4 c0 = counts4[(size_t)b * 512 + t * 2];
    int4 c1 = counts4[(size_t)b * 512 + t * 2 + 1];
    int s = c0.x + c0.y + c0.z + c0.w + c1.x + c1.y + c1.z + c1.w;
    ts[t] = s;
    __syncthreads();
    for (int d = 1; d < 256; d <<= 1) {
        int x = ts[t];
        int y = (t >= d) ? ts[t - d] : 0;
        __syncthreads();
        ts[t] = x + y;
        __syncthreads();
    }
    int base = bbase[b] + ((t == 0) ? 0 : ts[t - 1]);
    int4 o0, o1;
    o0.x = base;
    o0.y = o0.x + c0.x;
    o0.z = o0.y + c0.y;
    o0.w = o0.z + c0.z;
    o1.x = o0.w + c0.w;
    o1.y = o1.x + c1.x;
    o1.z = o1.y + c1.y;
    o1.w = o1.z + c1.z;
    off4[(size_t)b * 512 + t * 2] = o0;
    off4[(size_t)b * 512 + t * 2 + 1] = o1;
}

// ---------------- fused GRU via bf16 MFMA, weights staged in LDS -------------
#define QROWS 192                 // 2 mats * 3 gates * 32 cols
#define KPAD 136
__global__ __launch_bounds__(256) void gru_mfma_lds(const ushort* __restrict__ hb,
                                                    const float* __restrict__ hidden,
                                                    const ushort* __restrict__ wxt,
                                                    const ushort* __restrict__ wht,
                                                    const float* __restrict__ bx,
                                                    const float* __restrict__ bh,
                                                    float* __restrict__ out, int N) {
    __shared__ ushort lw[QROWS * KPAD];          // 51 KB
    int tid = threadIdx.x;
    int wid = tid >> 6, lane = tid & 63;
    int nstripes = (N + 15) >> 4;
    int stripe = blockIdx.x * 4 + wid;
    bool live = stripe < nstripes;
    int row0 = stripe * 16;
    int lr = lane & 15;
    int lk = (lane >> 4) * 8;

    short8 Ah[4], Ad[4];
    if (live) {
        const ushort* hrow = hb + (size_t)(row0 + lr) * D + lk;
        const float* drow = hidden + (size_t)(row0 + lr) * D + lk;
#pragma unroll
        for (int ks = 0; ks < 4; ++ks) {
            Ah[ks] = *(const short8*)(hrow + ks * 32);
            float4 c0 = *(const float4*)(drow + ks * 32);
            float4 c1 = *(const float4*)(drow + ks * 32 + 4);
            short8 vc;
            vc[0] = f2bf(c0.x); vc[1] = f2bf(c0.y); vc[2] = f2bf(c0.z); vc[3] = f2bf(c0.w);
            vc[4] = f2bf(c1.x); vc[5] = f2bf(c1.y); vc[6] = f2bf(c1.z); vc[7] = f2bf(c1.w);
            Ad[ks] = vc;
        }
    }
    int orow = row0 + (lane >> 4) * 4;

    for (int q = 0; q < 4; ++q) {
        if (q) __syncthreads();
        for (int j = tid; j < QROWS * 16; j += 256) {
            int chunk = j & 15;
            int row = j >> 4;
            int mat = row >= 96;
            int r = row - (mat ? 96 : 0);
            int g = r >> 5;
            int c = r & 31;
            const ushort* srcp = (mat ? wht : wxt)
                               + ((size_t)(g * 128 + q * 32 + c) << 7) + (chunk << 3);
            *(short8*)&lw[row * KPAD + chunk * 8] = *(const short8*)srcp;
        }
        __syncthreads();
        if (!live) continue;

#pragma unroll
        for (int mt = 0; mt < 2; ++mt) {
            int cl = mt * 16 + lr;
            const ushort* bx0 = lw + (0 * 32 + cl) * KPAD + lk;
            const ushort* bx1 = lw + (1 * 32 + cl) * KPAD + lk;
            const ushort* bx2 = lw + (2 * 32 + cl) * KPAD + lk;
            const ushort* bh0 = lw + ((96 + 0 * 32) + cl) * KPAD + lk;
            const ushort* bh1 = lw + ((96 + 1 * 32) + cl) * KPAD + lk;
            const ushort* bh2 = lw + ((96 + 2 * 32) + cl) * KPAD + lk;
            f32x4 ax0{}, ax1{}, ax2{}, ah0{}, ah1{}, ah2{};
#pragma unroll
            for (int ks = 0; ks < 4; ++ks) {
                short8 w0 = *(const short8*)(bx0 + ks * 32);
                short8 w1 = *(const short8*)(bx1 + ks * 32);
                short8 w2 = *(const short8*)(bx2 + ks * 32);
                short8 v0 = *(const short8*)(bh0 + ks * 32);
                short8 v1 = *(const short8*)(bh1 + ks * 32);
                short8 v2 = *(const short8*)(bh2 + ks * 32);
                ax0 = __builtin_amdgcn_mfma_f32_16x16x32_bf16(Ah[ks], w0, ax0, 0, 0, 0);
                ax1 = __builtin_amdgcn_mfma_f32_16x16x32_bf16(Ah[ks], w1, ax1, 0, 0, 0);
                ax2 = __builtin_amdgcn_mfma_f32_16x16x32_bf16(Ah[ks], w2, ax2, 0, 0, 0);
                ah0 = __builtin_amdgcn_mfma_f32_16x16x32_bf16(Ad[ks], v0, ah0, 0, 0, 0);
                ah1 = __builtin_amdgcn_mfma_f32_16x16x32_bf16(Ad[ks], v1, ah1, 0, 0, 0);
                ah2 = __builtin_amdgcn_mfma_f32_16x16x32_bf16(Ad[ks], v2, ah2, 0, 0, 0);
            }
            int col = q * 32 + mt * 16 + lr;
            float bxr = bx[col], bxi = bx[col + 128], bxn = bx[col + 256];
            float bhr = bh[col], bhi = bh[col + 128], bhn = bh[col + 256];
#pragma unroll
            for (int r = 0; r < 4; ++r) {
                int row = orow + r;
                if (row < N) {
                    float ir = ax0[r] + bxr, hr = ah0[r] + bhr;
                    float ii = ax1[r] + bxi, hi = ah1[r] + bhi;
                    float in_ = ax2[r] + bxn, hn = ah2[r] + bhn;
                    float rg = 1.f / (1.f + __expf(-(ir + hr)));
                    float ig = 1.f / (1.f + __expf(-(ii + hi)));
                    float nx = in_ + rg * hn;
                    float ng = 1.f - 2.f / (__expf(2.f * nx) + 1.f);   // tanh(nx)
                    float hv = hidden[(size_t)row * D + col];
                    out[(size_t)row * D + col] = ng + ig * (hv - ng);
                }
            }
        }
    }
}

extern "C" void kernel_launch(void* const* d_in, const int* in_sizes, int n_in,
                              void* d_out, int out_size, void* d_ws, size_t ws_size,
                              hipStream_t stream) {
    const float* x      = (const float*)d_in[0];
    const float* hidden = (const float*)d_in[1];
    const int*   adj_src = (const int*)d_in[2];
    const int*   adj_dst = (const int*)d_in[3];
    const float* adj_w   = (const float*)d_in[4];
    const float* gcn_W   = (const float*)d_in[5];
    const float* gcn_b   = (const float*)d_in[6];
    const float* x2h_W   = (const float*)d_in[7];
    const float* x2h_b   = (const float*)d_in[8];
    const float* h2h_W   = (const float*)d_in[9];
    const float* h2h_b   = (const float*)d_in[10];
    float* out = (float*)d_out;

    const int L = 2;
    const int N = in_sizes[0] / D;        // 50000
    const int E = in_sizes[2] / L;        // 800000
    const size_t nd = (size_t)N * D;

    const int NBH     = (N + 2047) / 2048;        // 25 scan blocks per half
    const int paddedH = NBH * 2048;               // 51200

    // Workspace ~43 MB (proven-safe envelope).
    char* ws = (char*)d_ws;
    ushort* P       = (ushort*)ws;                ws += nd * 2;   // support0 / support1
    ushort* Q       = (ushort*)ws;                ws += nd * 2;   // h1 / h2
    int*   counts2  = (int*)ws;                   ws += (size_t)2 * paddedH * 4;
    int*   offsets2 = (int*)ws;                   ws += ((size_t)2 * paddedH + 64) * 4;
    int*   bsum     = (int*)ws;                   ws += ((size_t)NBH + 64) * 4;
    int*   bbase    = (int*)ws;                   ws += ((size_t)NBH + 64) * 4;
    int2*  srcw0    = (int2*)ws;                  ws += (size_t)E * 8;
    int2*  srcw1    = (int2*)ws;                  ws += (size_t)E * 8;
    ushort* pl      = (ushort*)ws;                ws += (size_t)2 * E * 2;
    ushort* wxt     = (ushort*)ws;                ws += (size_t)384 * 128 * 2;
    ushort* wht     = (ushort*)ws;                ws += (size_t)384 * 128 * 2;

    int*   counts0  = counts2;
    int*   counts1  = counts2 + paddedH;
    int*   offsets0 = offsets2;
    int*   offsets1 = offsets2 + paddedH;
    ushort* pl0 = pl;
    ushort* pl1 = pl + E;

    const int* dst0 = adj_dst;
    const int* dst1 = adj_dst + E;
    const int* src0 = adj_src;
    const int* src1 = adj_src + E;
    const float* w0 = adj_w;
    const float* w1 = adj_w + E;

    dim3 blk(256);
    int batch_blocks = (N + ROWS_PB - 1) / ROWS_PB;       // 1563
    int gat_blocks   = (N + 3) / 4;                       // 12500
    int edge_blocks  = (E + 255) / 256;                   // 3125
    int zero_blocks  = (2 * paddedH / 4 + 255) / 256;     // 100
    int convw_blocks = (384 * 128 + 255) / 256;           // 192
    int nstripes     = (N + 15) / 16;
    int gru_blocks   = (nstripes + 3) / 4;

    // 1) zero both counter halves
    zero_int4<<<zero_blocks, blk, 0, stream>>>((int4*)counts2, 2 * paddedH / 4);
    // 2) gemm0 -> P | slot0 | convW
    fused_gs0<<<batch_blocks * 3 + convw_blocks, blk, 0, stream>>>(
        x, gcn_W, P, N, dst0, counts0, pl0, E, x2h_W, h2h_W, wxt, wht, batch_blocks);
    // 3) scan half 0
    scan_partial<<<NBH, blk, 0, stream>>>((const int4*)counts0, bsum);
    scan_base<<<1, 64, 0, stream>>>(bsum, bbase, NBH);
    scan_apply<<<NBH, blk, 0, stream>>>((const int4*)counts0, bbase, (int4*)offsets0);
    // 4) place0 | slot1
    fused_ps1<<<edge_blocks * 2, blk, 0, stream>>>(src0, dst0, w0, offsets0, pl0, srcw0,
                                                   dst1, counts1, pl1, E);
    // 5) scan half 1
    scan_partial<<<NBH, blk, 0, stream>>>((const int4*)counts1, bsum);
    scan_base<<<1, 64, 0, stream>>>(bsum, bbase, NBH);
    scan_apply<<<NBH, blk, 0, stream>>>((const int4*)counts1, bbase, (int4*)offsets1);
    // 6) gather0 (P->Q) | place1
    fused_gp1<<<edge_blocks * 5, blk, 0, stream>>>(P, srcw0, offsets0, gcn_b, Q, N,
                                                   src1, dst1, w1, offsets1, pl1,
                                                   srcw1, E);
    // 7) gemm1 (bf16 in): Q -> P
    gemm_rowbatch_bfin<<<batch_blocks, blk, 0, stream>>>(Q, gcn_W + (size_t)D * D, P, N);
    // 8) gather1: P -> Q
    gather_nodes_bf<<<gat_blocks, blk, 0, stream>>>(P, srcw1, offsets1, gcn_b + D, Q, N);
    // 9) GRU
    gru_mfma_lds<<<gru_blocks, blk, 0, stream>>>(Q, hidden, wxt, wht, x2h_b, h2h_b,
                                                 out, N);
}

// Round 15
// 306.825 us; speedup vs baseline: 1.0545x; 1.0545x over previous
//
#include <hip/hip_runtime.h>

#define D 128
#define RPW 8            // rows per wave (f32 GCN gemm)
#define ROWS_PB 32       // rows per block (4 waves * 8)

typedef __attribute__((ext_vector_type(8))) short short8;
typedef __attribute__((ext_vector_type(4))) float f32x4;

static __device__ __forceinline__ ushort f2bf(float f) {
    unsigned u = __float_as_uint(f);
    unsigned r = (u + 0x7fffu + ((u >> 16) & 1u)) >> 16;   // round-to-nearest-even
    return (ushort)r;
}

// ---------------- shared gemm compute (input staged in sh; W via pointer) ----
// sw may point to LDS or global (L2-resident) memory.
static __device__ __forceinline__ void gemm_compute(const float* sw, float (*sh)[D],
                                                    ushort* __restrict__ outb,
                                                    int N, int row0, int tid) {
    int wid = tid >> 6, lane = tid & 63;
    int rb = wid * RPW;
    float acc0[RPW], acc1[RPW];
#pragma unroll
    for (int r = 0; r < RPW; ++r) { acc0[r] = 0.f; acc1[r] = 0.f; }
    for (int k = 0; k < D; k += 4) {
        float w0[4], w1[4];
#pragma unroll
        for (int kk = 0; kk < 4; ++kk) {
            w0[kk] = sw[(k + kk) * D + lane];
            w1[kk] = sw[(k + kk) * D + lane + 64];
        }
#pragma unroll
        for (int r = 0; r < RPW; ++r) {
            float4 a4 = *(const float4*)&sh[rb + r][k];
            acc0[r] = fmaf(a4.x, w0[0], acc0[r]); acc1[r] = fmaf(a4.x, w1[0], acc1[r]);
            acc0[r] = fmaf(a4.y, w0[1], acc0[r]); acc1[r] = fmaf(a4.y, w1[1], acc1[r]);
            acc0[r] = fmaf(a4.z, w0[2], acc0[r]); acc1[r] = fmaf(a4.z, w1[2], acc1[r]);
            acc0[r] = fmaf(a4.w, w0[3], acc0[r]); acc1[r] = fmaf(a4.w, w1[3], acc1[r]);
        }
    }
#pragma unroll
    for (int r = 0; r < RPW; ++r) {
        int row = row0 + rb + r;
        if (row < N) {
            outb[(size_t)row * D + lane] = f2bf(acc0[r]);
            outb[(size_t)row * D + lane + 64] = f2bf(acc1[r]);
        }
    }
}

// ---------------- fused: gemm(layer0, W from L2) | slot histogram | convW ----
// Only 16 KB LDS (input rows) -> ~10 blocks/CU, so the slot role keeps its
// standalone occupancy while gemm overlaps the atomic stalls.
__global__ __launch_bounds__(256) void fused_sgc(const float* __restrict__ x,
                                                 const float* __restrict__ W0,
                                                 ushort* __restrict__ Abf, int N,
                                                 const int* __restrict__ adj_dst,
                                                 int* __restrict__ counts,
                                                 ushort* __restrict__ pl, int E2,
                                                 int E, int GB,
                                                 const float* __restrict__ Wx,
                                                 const float* __restrict__ Wh,
                                                 ushort* __restrict__ wxt,
                                                 ushort* __restrict__ wht) {
    __shared__ float sh[ROWS_PB][D];     // 16 KB only
    int bid = blockIdx.x, tid = threadIdx.x;
    int five = GB * 5;
    if (bid < five) {
        int g = bid / 5, j = bid - g * 5;
        if (j == 0) {
            int row0 = g * ROWS_PB;
            for (int i = tid; i < ROWS_PB * (D / 4); i += 256) {
                int r = i >> 5, c4 = i & 31;
                int row = row0 + r;
                float4 v = (row < N) ? ((const float4*)(x + (size_t)row * D))[c4]
                                     : make_float4(0.f, 0.f, 0.f, 0.f);
                ((float4*)sh)[i] = v;
            }
            __syncthreads();
            gemm_compute(W0, sh, Abf, N, row0, tid);     // W streamed from L2
        } else {
            int i = (g * 4 + j - 1) * 256 + tid;
            if (i < E2) {
                int off = (i >= E) ? N : 0;
                pl[i] = (ushort)atomicAdd(&counts[off + adj_dst[i]], 1);
            }
        }
    } else {
        int i = (bid - five) * 256 + tid;
        if (i < 384 * 128) {
            int c = i >> 7, k = i & 127;
            wxt[i] = f2bf(Wx[(size_t)k * 384 + c]);
            wht[i] = f2bf(Wh[(size_t)k * 384 + c]);
        }
    }
}

// ---------------- standalone gemm, bf16 input, W staged in LDS ---------------
__global__ __launch_bounds__(256) void gemm_rowbatch_bfin(const ushort* __restrict__ in,
                                                          const float* __restrict__ W,
                                                          ushort* __restrict__ outb, int N) {
    __shared__ float sw[D * D];
    __shared__ float sh[ROWS_PB][D];
    int tid = threadIdx.x;
    int row0 = blockIdx.x * ROWS_PB;
    for (int j = tid; j < D * D / 4; j += 256)
        ((float4*)sw)[j] = ((const float4*)W)[j];
    for (int i = tid; i < ROWS_PB * (D / 4); i += 256) {
        int r = i >> 5, c4 = i & 31;
        int row = row0 + r;
        float4 v;
        if (row < N) {
            uint2 u = ((const uint2*)(in + (size_t)row * D))[c4];
            v.x = __uint_as_float(u.x << 16);
            v.y = __uint_as_float(u.x & 0xffff0000u);
            v.z = __uint_as_float(u.y << 16);
            v.w = __uint_as_float(u.y & 0xffff0000u);
        } else {
            v = make_float4(0.f, 0.f, 0.f, 0.f);
        }
        ((float4*)sh)[i] = v;
    }
    __syncthreads();
    gemm_compute(sw, sh, outb, N, row0, tid);
}

// ---------------- zero ints --------------------------------------------------
__global__ void zero_int4(int4* __restrict__ p, int n4) {
    int i = blockIdx.x * blockDim.x + threadIdx.x;
    if (i < n4) p[i] = make_int4(0, 0, 0, 0);
}

// ---------------- multi-block scan: pass 1 (block partial sums) --------------
__global__ __launch_bounds__(256) void scan_partial(const int4* __restrict__ counts4,
                                                    int* __restrict__ bsum) {
    int b = blockIdx.x, t = threadIdx.x;
    int4 c0 = counts4[(size_t)b * 512 + t * 2];
    int4 c1 = counts4[(size_t)b * 512 + t * 2 + 1];
    int s = c0.x + c0.y + c0.z + c0.w + c1.x + c1.y + c1.z + c1.w;
#pragma unroll
    for (int d = 1; d < 64; d <<= 1) s += __shfl_xor(s, d);
    __shared__ int ws[4];
    if ((t & 63) == 0) ws[t >> 6] = s;
    __syncthreads();
    if (t == 0) bsum[b] = ws[0] + ws[1] + ws[2] + ws[3];
}

// ---------------- multi-block scan: pass 2 (scan of block sums, 1 wave) ------
__global__ void scan_base(const int* __restrict__ bsum, int* __restrict__ bbase, int nb) {
    int lane = threadIdx.x;   // launched with 64 threads
    int run = 0;
    for (int c = 0; c < nb; c += 64) {
        int v = (c + lane < nb) ? bsum[c + lane] : 0;
        int inc = v;
#pragma unroll
        for (int d = 1; d < 64; d <<= 1) {
            int y = __shfl_up(inc, d);
            if (lane >= d) inc += y;
        }
        if (c + lane < nb) bbase[c + lane] = run + inc - v;
        run += __shfl(inc, 63);
    }
}

// ---------------- multi-block scan: pass 3 (apply) ---------------------------
__global__ __launch_bounds__(256) void scan_apply(const int4* __restrict__ counts4,
                                                  const int* __restrict__ bbase,
                                                  int4* __restrict__ off4) {
    __shared__ int ts[256];
    int b = blockIdx.x, t = threadIdx.x;
    int4 c0 = counts4[(size_t)b * 512 + t * 2];
    int4 c1 = counts4[(size_t)b * 512 + t * 2 + 1];
    int s = c0.x + c0.y + c0.z + c0.w + c1.x + c1.y + c1.z + c1.w;
    ts[t] = s;
    __syncthreads();
    for (int d = 1; d < 256; d <<= 1) {
        int x = ts[t];
        int y = (t >= d) ? ts[t - d] : 0;
        __syncthreads();
        ts[t] = x + y;
        __syncthreads();
    }
    int base = bbase[b] + ((t == 0) ? 0 : ts[t - 1]);
    int4 o0, o1;
    o0.x = base;
    o0.y = o0.x + c0.x;
    o0.z = o0.y + c0.y;
    o0.w = o0.z + c0.z;
    o1.x = o0.w + c0.w;
    o1.y = o1.x + c1.x;
    o1.z = o1.y + c1.y;
    o1.w = o1.z + c1.z;
    off4[(size_t)b * 512 + t * 2] = o0;
    off4[(size_t)b * 512 + t * 2 + 1] = o1;
}

// ---------------- place both layers: srcw_l[offsets[dst]+pl] = (src,w) -------
__global__ void place2_kernel(const int* __restrict__ src, const int* __restrict__ dst,
                              const float* __restrict__ w,
                              const int* __restrict__ offsets2,
                              const ushort* __restrict__ pl,
                              int2* __restrict__ srcw0, int2* __restrict__ srcw1,
                              int E, int E2, int N) {
    int i = blockIdx.x * blockDim.x + threadIdx.x;
    if (i >= E2) return;
    int l1 = i >= E;
    int node = dst[i];
    int p = offsets2[(l1 ? N : 0) + node] - (l1 ? E : 0) + (int)pl[i];
    int2 v = make_int2(src[i], __float_as_int(w[i]));
    (l1 ? srcw1 : srcw0)[p] = v;
}

// ---------------- gather helper (bf16 support rows) --------------------------
static __device__ __forceinline__ void gather_row(const ushort* __restrict__ base,
                                                  const int2* __restrict__ srcw,
                                                  int lo, int hi,
                                                  float& ax, float& ay) {
    ax = 0.f; ay = 0.f;
    int j = lo;
    for (; j + 8 <= hi; j += 8) {
        int2 s[8];
        uint v[8];
#pragma unroll
        for (int u = 0; u < 8; ++u) s[u] = srcw[j + u];
#pragma unroll
        for (int u = 0; u < 8; ++u)
            v[u] = *(const uint*)(base + ((size_t)s[u].x << 7));
#pragma unroll
        for (int u = 0; u < 8; ++u) {
            float wt = __int_as_float(s[u].y);
            ax = fmaf(wt, __uint_as_float(v[u] << 16), ax);
            ay = fmaf(wt, __uint_as_float(v[u] & 0xffff0000u), ay);
        }
    }
    for (; j < hi; ++j) {
        int2 sw = srcw[j];
        float wt = __int_as_float(sw.y);
        uint v = *(const uint*)(base + ((size_t)sw.x << 7));
        ax = fmaf(wt, __uint_as_float(v << 16), ax);
        ay = fmaf(wt, __uint_as_float(v & 0xffff0000u), ay);
    }
}

// ---------------- gather -> bf16 out (both layers) ---------------------------
__global__ void gather_nodes_bf(const ushort* __restrict__ supb,
                                const int2* __restrict__ srcw,
                                const int* __restrict__ offsets, int sub,
                                const float* __restrict__ bias,
                                ushort* __restrict__ outb, int N) {
    int node = (blockIdx.x * blockDim.x + threadIdx.x) >> 6;
    int lane = threadIdx.x & 63;
    if (node >= N) return;
    int lo = offsets[node] - sub, hi = offsets[node + 1] - sub;
    int c = lane * 2;
    float ax, ay;
    gather_row(supb + c, srcw, lo, hi, ax, ay);
    float2 bi = *(const float2*)(bias + c);
    uint pk = ((uint)f2bf(fmaxf(ay + bi.y, 0.f)) << 16) | (uint)f2bf(fmaxf(ax + bi.x, 0.f));
    *(uint*)(outb + (size_t)node * D + c) = pk;
}

// ---------------- fused GRU via bf16 MFMA, weights staged in LDS -------------
#define QROWS 192                 // 2 mats * 3 gates * 32 cols
#define KPAD 136
__global__ __launch_bounds__(256) void gru_mfma_lds(const ushort* __restrict__ hb,
                                                    const float* __restrict__ hidden,
                                                    const ushort* __restrict__ wxt,
                                                    const ushort* __restrict__ wht,
                                                    const float* __restrict__ bx,
                                                    const float* __restrict__ bh,
                                                    float* __restrict__ out, int N) {
    __shared__ ushort lw[QROWS * KPAD];          // 51 KB
    int tid = threadIdx.x;
    int wid = tid >> 6, lane = tid & 63;
    int nstripes = (N + 15) >> 4;
    int stripe = blockIdx.x * 4 + wid;
    bool live = stripe < nstripes;
    int row0 = stripe * 16;
    int lr = lane & 15;
    int lk = (lane >> 4) * 8;

    short8 Ah[4], Ad[4];
    if (live) {
        const ushort* hrow = hb + (size_t)(row0 + lr) * D + lk;
        const float* drow = hidden + (size_t)(row0 + lr) * D + lk;
#pragma unroll
        for (int ks = 0; ks < 4; ++ks) {
            Ah[ks] = *(const short8*)(hrow + ks * 32);
            float4 c0 = *(const float4*)(drow + ks * 32);
            float4 c1 = *(const float4*)(drow + ks * 32 + 4);
            short8 vc;
            vc[0] = f2bf(c0.x); vc[1] = f2bf(c0.y); vc[2] = f2bf(c0.z); vc[3] = f2bf(c0.w);
            vc[4] = f2bf(c1.x); vc[5] = f2bf(c1.y); vc[6] = f2bf(c1.z); vc[7] = f2bf(c1.w);
            Ad[ks] = vc;
        }
    }
    int orow = row0 + (lane >> 4) * 4;

    for (int q = 0; q < 4; ++q) {
        if (q) __syncthreads();
        for (int j = tid; j < QROWS * 16; j += 256) {
            int chunk = j & 15;
            int row = j >> 4;
            int mat = row >= 96;
            int r = row - (mat ? 96 : 0);
            int g = r >> 5;
            int c = r & 31;
            const ushort* srcp = (mat ? wht : wxt)
                               + ((size_t)(g * 128 + q * 32 + c) << 7) + (chunk << 3);
            *(short8*)&lw[row * KPAD + chunk * 8] = *(const short8*)srcp;
        }
        __syncthreads();
        if (!live) continue;

#pragma unroll
        for (int mt = 0; mt < 2; ++mt) {
            int cl = mt * 16 + lr;
            const ushort* bx0 = lw + (0 * 32 + cl) * KPAD + lk;
            const ushort* bx1 = lw + (1 * 32 + cl) * KPAD + lk;
            const ushort* bx2 = lw + (2 * 32 + cl) * KPAD + lk;
            const ushort* bh0 = lw + ((96 + 0 * 32) + cl) * KPAD + lk;
            const ushort* bh1 = lw + ((96 + 1 * 32) + cl) * KPAD + lk;
            const ushort* bh2 = lw + ((96 + 2 * 32) + cl) * KPAD + lk;
            f32x4 ax0{}, ax1{}, ax2{}, ah0{}, ah1{}, ah2{};
#pragma unroll
            for (int ks = 0; ks < 4; ++ks) {
                short8 w0 = *(const short8*)(bx0 + ks * 32);
                short8 w1 = *(const short8*)(bx1 + ks * 32);
                short8 w2 = *(const short8*)(bx2 + ks * 32);
                short8 v0 = *(const short8*)(bh0 + ks * 32);
                short8 v1 = *(const short8*)(bh1 + ks * 32);
                short8 v2 = *(const short8*)(bh2 + ks * 32);
                ax0 = __builtin_amdgcn_mfma_f32_16x16x32_bf16(Ah[ks], w0, ax0, 0, 0, 0);
                ax1 = __builtin_amdgcn_mfma_f32_16x16x32_bf16(Ah[ks], w1, ax1, 0, 0, 0);
                ax2 = __builtin_amdgcn_mfma_f32_16x16x32_bf16(Ah[ks], w2, ax2, 0, 0, 0);
                ah0 = __builtin_amdgcn_mfma_f32_16x16x32_bf16(Ad[ks], v0, ah0, 0, 0, 0);
                ah1 = __builtin_amdgcn_mfma_f32_16x16x32_bf16(Ad[ks], v1, ah1, 0, 0, 0);
                ah2 = __builtin_amdgcn_mfma_f32_16x16x32_bf16(Ad[ks], v2, ah2, 0, 0, 0);
            }
            int col = q * 32 + mt * 16 + lr;
            float bxr = bx[col], bxi = bx[col + 128], bxn = bx[col + 256];
            float bhr = bh[col], bhi = bh[col + 128], bhn = bh[col + 256];
#pragma unroll
            for (int r = 0; r < 4; ++r) {
                int row = orow + r;
                if (row < N) {
                    float ir = ax0[r] + bxr, hr = ah0[r] + bhr;
                    float ii = ax1[r] + bxi, hi = ah1[r] + bhi;
                    float in_ = ax2[r] + bxn, hn = ah2[r] + bhn;
                    float rg = 1.f / (1.f + __expf(-(ir + hr)));
                    float ig = 1.f / (1.f + __expf(-(ii + hi)));
                    float nx = in_ + rg * hn;
                    float ng = 1.f - 2.f / (__expf(2.f * nx) + 1.f);   // tanh(nx)
                    float hv = hidden[(size_t)row * D + col];
                    out[(size_t)row * D + col] = ng + ig * (hv - ng);
                }
            }
        }
    }
}

extern "C" void kernel_launch(void* const* d_in, const int* in_sizes, int n_in,
                              void* d_out, int out_size, void* d_ws, size_t ws_size,
                              hipStream_t stream) {
    const float* x      = (const float*)d_in[0];
    const float* hidden = (const float*)d_in[1];
    const int*   adj_src = (const int*)d_in[2];
    const int*   adj_dst = (const int*)d_in[3];
    const float* adj_w   = (const float*)d_in[4];
    const float* gcn_W   = (const float*)d_in[5];
    const float* gcn_b   = (const float*)d_in[6];
    const float* x2h_W   = (const float*)d_in[7];
    const float* x2h_b   = (const float*)d_in[8];
    const float* h2h_W   = (const float*)d_in[9];
    const float* h2h_b   = (const float*)d_in[10];
    float* out = (float*)d_out;

    const int L = 2;
    const int N = in_sizes[0] / D;        // 50000
    const int E = in_sizes[2] / L;        // 800000
    const size_t nd = (size_t)N * D;

    const int twoN   = 2 * N;
    const int NB     = (twoN + 2047) / 2048;      // scan blocks (49)
    const int padded = NB * 2048;

    // Workspace ~43 MB (proven-safe envelope).
    char* ws = (char*)d_ws;
    ushort* P       = (ushort*)ws;                ws += nd * 2;   // support0 / support1
    ushort* Q       = (ushort*)ws;                ws += nd * 2;   // h1 / h2
    int*   counts2  = (int*)ws;                   ws += (size_t)padded * 4;
    int*   offsets2 = (int*)ws;                   ws += ((size_t)padded + 64) * 4;
    int*   bsum     = (int*)ws;                   ws += ((size_t)NB + 64) * 4;
    int*   bbase    = (int*)ws;                   ws += ((size_t)NB + 64) * 4;
    int2*  srcw0    = (int2*)ws;                  ws += (size_t)E * 8;
    int2*  srcw1    = (int2*)ws;                  ws += (size_t)E * 8;
    ushort* pl      = (ushort*)ws;                ws += (size_t)2 * E * 2;
    ushort* wxt     = (ushort*)ws;                ws += (size_t)384 * 128 * 2;
    ushort* wht     = (ushort*)ws;                ws += (size_t)384 * 128 * 2;

    dim3 blk(256);
    int batch_blocks = (N + ROWS_PB - 1) / ROWS_PB;       // 1563
    int gat_blocks   = (N + 3) / 4;
    int e2_blocks    = (2 * E + 255) / 256;               // 6250
    int zero_blocks  = (padded / 4 + 255) / 256;
    int convw_blocks = (384 * 128 + 255) / 256;           // 192
    int nstripes     = (N + 15) / 16;
    int gru_blocks   = (nstripes + 3) / 4;

    // 1) zero counters
    zero_int4<<<zero_blocks, blk, 0, stream>>>((int4*)counts2, padded / 4);
    // 2) fused interleaved: gemm layer0 (W via L2) -> P | slot histogram | convW
    fused_sgc<<<batch_blocks * 5 + convw_blocks, blk, 0, stream>>>(
        x, gcn_W, P, N, adj_dst, counts2, pl, 2 * E, E, batch_blocks,
        x2h_W, h2h_W, wxt, wht);
    // 3) scan
    scan_partial<<<NB, blk, 0, stream>>>((const int4*)counts2, bsum);
    scan_base<<<1, 64, 0, stream>>>(bsum, bbase, NB);
    scan_apply<<<NB, blk, 0, stream>>>((const int4*)counts2, bbase, (int4*)offsets2);
    // 4) place both layers (atomic-free)
    place2_kernel<<<e2_blocks, blk, 0, stream>>>(adj_src, adj_dst, adj_w, offsets2, pl,
                                                 srcw0, srcw1, E, 2 * E, N);
    // 5) gather0: P -> Q (h1, bf16)
    gather_nodes_bf<<<gat_blocks, blk, 0, stream>>>(P, srcw0, offsets2, 0,
                                                    gcn_b, Q, N);
    // 6) gemm1 (bf16 in): Q -> P (support1, bf16)
    gemm_rowbatch_bfin<<<batch_blocks, blk, 0, stream>>>(Q, gcn_W + (size_t)D * D,
                                                         P, N);
    // 7) gather1: P -> Q (h2, bf16)
    gather_nodes_bf<<<gat_blocks, blk, 0, stream>>>(P, srcw1, offsets2 + N, E,
                                                    gcn_b + D, Q, N);
    // 8) GRU
    gru_mfma_lds<<<gru_blocks, blk, 0, stream>>>(Q, hidden, wxt, wht, x2h_b, h2h_b,
                                                 out, N);
}